// Round 7
// baseline (840.269 us; speedup 1.0000x reference)
//
#include <hip/hip_runtime.h>

// AugmentedNeuralODE, round 20: hybrid table residency.
// R19 postmortem: spill fixed (FETCH 574KB) but ALL tables in LDS with a
// [cls][p] layout = 4-way bank conflicts (1.93e7) + ~88 latency-exposed
// ds_reads gating every feval -> wall 5830 cyc/feval (> R13's 3770).
// R20:
//   * L1 tables (w1x,w1y f32x2 x8 = 32 regs; w1t,bb1 bf16-packed = 16)
//     live in VGPRs, PARKED via opaque asm (defeats remat -- R17 lesson).
//     Arch half ledger: 48 tables + ~70 working = ~118 <= 128. AGPR half
//     = 128 (all of W2, parked, MFMA A-src direct).
//   * Epilogue tables in LDS, TRANSPOSED to [...][cls] (cls-stride 16B ->
//     banks 4c..4c+3, 8-way broadcast, conflict-free), volatile reads
//     (13/feval) scheduled under the MFMAs.
//   * anti-phase stagger: s_sleep by ((blk&1)<<1|w)*~512cyc so the two
//     waves/SIMD interleave trans bursts instead of colliding.
// Else identical to R19: duplicate-column 2-wave blocks, shfl_xor(8)
// exchange, pair-fused epilogue, no in-loop barriers, 1024x128.

#define HID 128
#define TT  8
#define F(a,b) ((float)((double)(a)/(double)(b)))
#define K2C 2.8853900817779268f        // 2*log2(e), folded into W1/b1/W2/b2

typedef __attribute__((ext_vector_type(8))) short bf16x8;
typedef __attribute__((ext_vector_type(4))) float f32x4;
typedef __attribute__((ext_vector_type(2))) float f32x2;

union Frag { bf16x8 v; unsigned short u[8]; unsigned int d[4]; };

__device__ __forceinline__ f32x2 bc(float s) { return f32x2{s, s}; }
__device__ __forceinline__ f32x2 pk_fma(f32x2 a, f32x2 b, f32x2 c) {
#if __has_builtin(__builtin_elementwise_fma)
  return __builtin_elementwise_fma(a, b, c);
#else
  return a * b + c;
#endif
}
__device__ __forceinline__ float exp2_fast(float x) {
#if __has_builtin(__builtin_amdgcn_exp2f)
  return __builtin_amdgcn_exp2f(x);
#else
  return __builtin_exp2f(x);
#endif
}
__device__ __forceinline__ unsigned short f2bf(float f) {
  unsigned u = __builtin_bit_cast(unsigned, f);
  u += 0x7FFFu + ((u >> 16) & 1u);          // RNE
  return (unsigned short)(u >> 16);
}
__device__ __forceinline__ unsigned pack2bf(float a, float b) {
#if __has_builtin(__builtin_amdgcn_cvt_pk_bf16_f32)
  auto pk = __builtin_amdgcn_cvt_pk_bf16_f32(a, b);   // v_cvt_pk_bf16_f32
  return __builtin_bit_cast(unsigned, pk);
#else
  unsigned ua = __builtin_bit_cast(unsigned, a);
  unsigned ub = __builtin_bit_cast(unsigned, b);
  ua += 0x7FFFu + ((ua >> 16) & 1u);
  ub += 0x7FFFu + ((ub >> 16) & 1u);
  return __builtin_amdgcn_perm(ub, ua, 0x07060302u);
#endif
}
// u pre-scaled by 2*log2(e): q = 1/(exp2(u)+1), separate rcp per element.
__device__ __forceinline__ f32x2 sig_q(f32x2 u) {
  f32x2 e;
  e.x = exp2_fast(u.x);
  e.y = exp2_fast(u.y);
  f32x2 d = e + bc(1.0f);
  f32x2 q;
  q.x = __builtin_amdgcn_rcpf(d.x);
  q.y = __builtin_amdgcn_rcpf(d.y);
  return q;
}
__device__ __forceinline__ f32x2 tanh_pre(f32x2 u) {   // tanh = 1 - 2q
  return pk_fma(bc(-2.0f), sig_q(u), bc(1.0f));
}
__device__ __forceinline__ float bfhi(unsigned d) {
  return __builtin_bit_cast(float, d & 0xFFFF0000u);
}
__device__ __forceinline__ float bflo(unsigned d) {
  return __builtin_bit_cast(float, d << 16);
}

// epilogue tables, [cls] innermost (16B stride -> conflict-free broadcast)
struct EpiT {
  f32x4 w3n2[4][2][8];   // [p][p2][cls] = {-2w3 rr=2p2, -2w3 rr=2p2+1}
  f32x4 b2k[4][8];       // [p][cls]     = b2[ub..ub+3]*K2C
  f32x2 w3s[8];          // [cls]
};

__global__ __launch_bounds__(128, 2) void node_kernel(
    const float* __restrict__ r0, const float* __restrict__ tarr,
    const float* __restrict__ W1, const float* __restrict__ b1,
    const float* __restrict__ W2, const float* __restrict__ b2,
    const float* __restrict__ W3, const float* __restrict__ b3,
    float* __restrict__ out)
{
  const int tid  = (int)threadIdx.x;
  const int w    = tid >> 6;            // wave 0/1
  const int lane = tid & 63;
  const int q    = lane >> 4;           // 0..3
  const int h    = (lane >> 3) & 1;     // half within 16-col group
  const int c    = lane & 7;            // my sample (0..7 within wave)
  const int m16  = lane & 15;           // MFMA row/col index
  const int cls  = h * 4 + q;           // lane class
  const int s    = (int)blockIdx.x * 16 + w * 8 + c;
  const bool hb  = (h != 0);

  __shared__ EpiT et;                   // 1.6 KB

  // ---- build epilogue tables: one writer lane per class ----
  if (w == 0 && c == 0) {
    f32x2 ws = bc(0.f);
    #pragma unroll
    for (int p = 0; p < 4; ++p) {
      int ub = (h * 4 + p) * 16 + q * 4;
      et.b2k[p][cls] = f32x4{b2[ub] * K2C, b2[ub + 1] * K2C,
                             b2[ub + 2] * K2C, b2[ub + 3] * K2C};
      #pragma unroll
      for (int p2 = 0; p2 < 2; ++p2) {
        f32x2 w3a = f32x2{W3[(ub + 2 * p2) * 2], W3[(ub + 2 * p2) * 2 + 1]};
        f32x2 w3b = f32x2{W3[(ub + 2 * p2 + 1) * 2], W3[(ub + 2 * p2 + 1) * 2 + 1]};
        ws += w3a + w3b;
        et.w3n2[p][p2][cls] =
            f32x4{-2.f * w3a.x, -2.f * w3a.y, -2.f * w3b.x, -2.f * w3b.y};
      }
    }
    et.w3s[cls] = ws;
  }

  // ---- W2: all 8 tiles x 4 slabs -> AGPR (128 regs), K2C-folded ----
  Frag W2a[8][4];
  #pragma unroll
  for (int t = 0; t < 8; ++t)
    #pragma unroll
    for (int kk = 0; kk < 4; ++kk) {
      #pragma unroll
      for (int j = 0; j < 8; ++j)
        W2a[t][kk].u[j] = f2bf(W2[(kk * 32 + q * 8 + j) * HID + (t * 16 + m16)] * K2C);
      asm volatile("" : "+a"(W2a[t][kk].v));   // park in AGPR
    }

  // ---- L1 tables -> VGPRs, parked (48 regs, remat-proof) ----
  f32x2 w1x[8], w1y[8];
  unsigned w1tp[8], bb1p[8];            // bf16-packed
  #pragma unroll
  for (int p = 0; p < 8; ++p) {
    int sl = p >> 2, pp = p & 3;
    int u = (2 * h + sl) * 32 + q * 8 + 2 * pp;
    w1x[p] = f32x2{W1[0 * HID + u], W1[0 * HID + u + 1]} * bc(K2C);
    w1y[p] = f32x2{W1[1 * HID + u], W1[1 * HID + u + 1]} * bc(K2C);
    w1tp[p] = pack2bf(W1[4 * HID + u] * K2C, W1[4 * HID + u + 1] * K2C);
    bb1p[p] = pack2bf(b1[u] * K2C, b1[u + 1] * K2C);
    asm volatile("" : "+v"(w1x[p]), "+v"(w1y[p]), "+v"(w1tp[p]), "+v"(bb1p[p]));
  }

  const f32x2 b3v = f32x2{b3[0], b3[1]};

  __syncthreads();                      // et ready (only barrier)

  // anti-phase stagger: ~512cyc per step, covers both wave-pairing modes
  {
    int sidx = (((int)blockIdx.x & 1) << 1) | w;   // 0..3
    for (int i = 0; i < sidx; ++i) __builtin_amdgcn_s_sleep(8);
  }

  f32x2 S = f32x2{r0[2 * s + 0], r0[2 * s + 1]};
  if (lane < 8) *(float2*)&out[(s * TT + 0) * 2] = make_float2(S.x, S.y);

  auto feval = [&](float tt, f32x2 st) -> f32x2 {
    const f32x2 sx = bc(st.x), sy = bc(st.y), tv = bc(tt);
    // ---- L1: my 2 slabs (8 tanh-pairs, 32 trans), tables in regs ----
    unsigned own[2][4];
    #pragma unroll
    for (int sl = 0; sl < 2; ++sl)
      #pragma unroll
      for (int pp = 0; pp < 4; ++pp) {
        int p = sl * 4 + pp;
        f32x2 bb = f32x2{bflo(bb1p[p]), bfhi(bb1p[p])};
        f32x2 wt = f32x2{bflo(w1tp[p]), bfhi(w1tp[p])};
        f32x2 a = pk_fma(sx, w1x[p], bb);
        a = pk_fma(sy, w1y[p], a);
        a = pk_fma(tv, wt, a);
        f32x2 hv = tanh_pre(a);
        own[sl][pp] = pack2bf(hv.x, hv.y);
      }
    // ---- exchange with lane^8 (partner has the other 2 slabs) ----
    unsigned rcv[2][4];
    #pragma unroll
    for (int sl = 0; sl < 2; ++sl)
      #pragma unroll
      for (int d = 0; d < 4; ++d)
        rcv[sl][d] = __shfl_xor(own[sl][d], 8);
    // canonical slab-order B frags (cols 8..15 duplicate cols 0..7)
    Frag B[4];
    #pragma unroll
    for (int d = 0; d < 4; ++d) {
      B[0].d[d] = hb ? rcv[0][d] : own[0][d];
      B[1].d[d] = hb ? rcv[1][d] : own[1][d];
      B[2].d[d] = hb ? own[0][d] : rcv[0][d];
      B[3].d[d] = hb ? own[1][d] : rcv[1][d];
    }
    // ---- pair-fused MFMA+epilogue; epi tables via volatile LDS reads ----
    const volatile EpiT* E = &et;
    f32x2 ws0 = *(const volatile f32x2*)&E->w3s[cls];
    f32x2 vsa[2] = {ws0, bc(0.f)};
    #pragma unroll
    for (int p = 0; p < 4; ++p) {
      f32x4 w3q0 = *(const volatile f32x4*)&E->w3n2[p][0][cls];
      f32x4 w3q1 = *(const volatile f32x4*)&E->w3n2[p][1][cls];
      f32x4 b2q  = *(const volatile f32x4*)&E->b2k[p][cls];
      f32x4 aA, aB;
      #pragma unroll
      for (int kk = 0; kk < 4; ++kk) {
        aA = __builtin_amdgcn_mfma_f32_16x16x32_bf16(
            W2a[p][kk].v, B[kk].v,
            kk == 0 ? f32x4{0.f, 0.f, 0.f, 0.f} : aA, 0, 0, 0);
        aB = __builtin_amdgcn_mfma_f32_16x16x32_bf16(
            W2a[p + 4][kk].v, B[kk].v,
            kk == 0 ? f32x4{0.f, 0.f, 0.f, 0.f} : aB, 0, 0, 0);
      }
      #pragma unroll
      for (int p2 = 0; p2 < 2; ++p2) {
        f32x4 w3q = p2 ? w3q1 : w3q0;
        float e0 = hb ? aB[2 * p2]     : aA[2 * p2];
        float e1 = hb ? aB[2 * p2 + 1] : aA[2 * p2 + 1];
        f32x2 av = f32x2{e0 + b2q[2 * p2], e1 + b2q[2 * p2 + 1]};
        f32x2 qv = sig_q(av);
        vsa[p & 1] = pk_fma(bc(qv.x), f32x2{w3q[0], w3q[1]}, vsa[p & 1]);
        vsa[p & 1] = pk_fma(bc(qv.y), f32x2{w3q[2], w3q[3]}, vsa[p & 1]);
      }
    }
    f32x2 vs = vsa[0] + vsa[1];
    // reduce over the 8 lanes of sample c: xor8 (h), xor16/32 (q)
    float px = vs.x, py = vs.y;
    px += __shfl_xor(px, 8);  py += __shfl_xor(py, 8);
    px += __shfl_xor(px, 16); py += __shfl_xor(py, 16);
    px += __shfl_xor(px, 32); py += __shfl_xor(py, 32);
    return f32x2{px, py} + b3v;
  };

  #pragma unroll 1
  for (int iv = 0; iv < TT - 1; ++iv) {
    float t0 = tarr[iv], t1 = tarr[iv + 1];
    float dt = (t1 - t0) * 0.5f;
    #pragma unroll 1
    for (int ss = 0; ss < 2; ++ss) {
      float tb0 = (ss == 0) ? t0 : (t0 + dt);
      const f32x2 dtv = bc(dt);
      f32x2 k1 = feval(tb0, S);
      f32x2 k2 = feval(tb0 + dt * F(1,5), pk_fma(bc(dt * F(1,5)), k1, S));
      f32x2 a3 = pk_fma(bc(F(9,40)), k2, bc(F(3,40)) * k1);
      f32x2 k3 = feval(tb0 + dt * F(3,10), pk_fma(dtv, a3, S));
      f32x2 a4 = pk_fma(bc(F(44,45)), k1,
                 pk_fma(bc(-F(56,15)), k2, bc(F(32,9)) * k3));
      f32x2 k4 = feval(tb0 + dt * F(4,5), pk_fma(dtv, a4, S));
      f32x2 a5 = pk_fma(bc(F(19372,6561)), k1,
                 pk_fma(bc(-F(25360,2187)), k2,
                 pk_fma(bc(F(64448,6561)), k3, bc(-F(212,729)) * k4)));
      f32x2 k5 = feval(tb0 + dt * F(8,9), pk_fma(dtv, a5, S));
      f32x2 a6 = pk_fma(bc(F(9017,3168)), k1,
                 pk_fma(bc(-F(355,33)), k2,
                 pk_fma(bc(F(46732,5247)), k3,
                 pk_fma(bc(F(49,176)), k4, bc(-F(5103,18656)) * k5))));
      f32x2 k6 = feval(tb0 + dt, pk_fma(dtv, a6, S));
      f32x2 fin = pk_fma(bc(F(35,384)), k1,
                  pk_fma(bc(F(500,1113)), k3,
                  pk_fma(bc(F(125,192)), k4,
                  pk_fma(bc(-F(2187,6784)), k5, bc(F(11,84)) * k6))));
      S = pk_fma(dtv, fin, S);
    }
    if (lane < 8)
      *(float2*)&out[(s * TT + iv + 1) * 2] = make_float2(S.x, S.y);
  }
}

extern "C" void kernel_launch(void* const* d_in, const int* in_sizes, int n_in,
                              void* d_out, int out_size, void* d_ws, size_t ws_size,
                              hipStream_t stream) {
  const float* r0 = (const float*)d_in[0];
  const float* t  = (const float*)d_in[1];
  const float* W1 = (const float*)d_in[2];
  const float* b1 = (const float*)d_in[3];
  const float* W2 = (const float*)d_in[4];
  const float* b2 = (const float*)d_in[5];
  const float* W3 = (const float*)d_in[6];
  const float* b3 = (const float*)d_in[7];
  float* out = (float*)d_out;
  const int B = in_sizes[0] / 2;        // 16384
  dim3 grid(B / 16), block(128);        // 1024 blocks x 2 waves (8 samp/wave)
  node_kernel<<<grid, block, 0, stream>>>(r0, t, W1, b1, W2, b2, W3, b3, out);
}